// Round 1
// baseline (623.167 us; speedup 1.0000x reference)
//
#include <hip/hip_runtime.h>

#define T_TOKENS 8192
#define MDIM 1024
#define NEXP 8
#define DFF_DIM 4096
#define CAP 1280

typedef __attribute__((ext_vector_type(8))) short short8;
typedef __attribute__((ext_vector_type(4))) float f32x4;

__device__ inline unsigned short f2bf(float f) {
  unsigned u = __float_as_uint(f);
  u = u + 0x7fffu + ((u >> 16) & 1u);
  return (unsigned short)(u >> 16);
}

// ---------------- gating: logits in fp64, softmax top-1 ----------------
__global__ __launch_bounds__(64) void gate_kernel(const float* __restrict__ x,
    const float* __restrict__ wg, int* __restrict__ eidx, float* __restrict__ gate)
{
  const int t = blockIdx.x;
  const int lane = threadIdx.x;
  const float* xr = x + (size_t)t * MDIM;
  double acc[NEXP];
  #pragma unroll
  for (int e = 0; e < NEXP; ++e) acc[e] = 0.0;
  for (int m = lane; m < MDIM; m += 64) {
    double xv = (double)xr[m];
    const float* wr = wg + (size_t)m * NEXP;
    #pragma unroll
    for (int e = 0; e < NEXP; ++e) acc[e] += xv * (double)wr[e];
  }
  #pragma unroll
  for (int off = 32; off > 0; off >>= 1) {
    #pragma unroll
    for (int e = 0; e < NEXP; ++e) acc[e] += __shfl_down(acc[e], off);
  }
  if (lane == 0) {
    double mx = acc[0]; int idx = 0;
    #pragma unroll
    for (int e = 1; e < NEXP; ++e) if (acc[e] > mx) { mx = acc[e]; idx = e; }
    double s = 0.0;
    #pragma unroll
    for (int e = 0; e < NEXP; ++e) s += exp(acc[e] - mx);
    eidx[t] = idx;
    gate[t] = (float)(1.0 / s);   // softmax prob of argmax expert
  }
}

// ---------------- order-preserving capacity scan (single block) ----------------
__global__ __launch_bounds__(1024) void scan_kernel(const int* __restrict__ eidx,
    int* __restrict__ slot_token, int* __restrict__ filled)
{
  __shared__ int hist[16][NEXP];
  __shared__ int wpre[16][NEXP];
  __shared__ int rtot[NEXP];
  __shared__ int base[NEXP];
  const int tid = threadIdx.x;
  const int w = tid >> 6, lane = tid & 63;
  for (int i = tid; i < NEXP * CAP; i += 1024) slot_token[i] = -1;
  if (tid < NEXP) base[tid] = 0;
  __syncthreads();
  const unsigned long long lt = (1ull << lane) - 1ull;
  for (int r = 0; r < T_TOKENS / 1024; ++r) {
    const int t = r * 1024 + tid;
    const int e = eidx[t];
    unsigned long long bal[NEXP];
    #pragma unroll
    for (int ee = 0; ee < NEXP; ++ee) bal[ee] = __ballot(e == ee);
    const int rank = __popcll(bal[e] & lt);
    if (lane < NEXP) hist[w][lane] = __popcll(bal[lane]);
    __syncthreads();
    if (tid < 16 * NEXP) {
      int ww = tid >> 3, ee = tid & 7, s = 0;
      for (int j = 0; j < ww; ++j) s += hist[j][ee];
      wpre[ww][ee] = s;
    }
    if (tid < NEXP) {
      int s = 0;
      for (int j = 0; j < 16; ++j) s += hist[j][tid];
      rtot[tid] = s;
    }
    __syncthreads();
    const int pos = base[e] + wpre[w][e] + rank;
    if (pos < CAP) slot_token[e * CAP + pos] = t;
    __syncthreads();
    if (tid < NEXP) base[tid] += rtot[tid];
    __syncthreads();
  }
  if (tid < NEXP) filled[tid] = (base[tid] < CAP) ? base[tid] : CAP;
}

// ---------------- dispatch: gather kept tokens into [E,C,M] bf16 ----------------
__global__ __launch_bounds__(256) void dispatch_kernel(const float* __restrict__ x,
    const int* __restrict__ slot_token, unsigned short* __restrict__ Abuf)
{
  const int row = blockIdx.x;
  const int tid = threadIdx.x;
  const int t = slot_token[row];
  unsigned short* dst = Abuf + (size_t)row * MDIM + tid * 4;
  if (t < 0) {
    ushort4 z; z.x = 0; z.y = 0; z.z = 0; z.w = 0;
    *(ushort4*)dst = z;
  } else {
    const float4 v = *(const float4*)(x + (size_t)t * MDIM + tid * 4);
    ushort4 h;
    h.x = f2bf(v.x); h.y = f2bf(v.y); h.z = f2bf(v.z); h.w = f2bf(v.w);
    *(ushort4*)dst = h;
  }
}

// ---------------- batched expert GEMM, bf16 MFMA 16x16x32 ----------------
// MODE 0: H = relu(A @ W1 + b1)  -> bf16, A=[C,M] bf16, W1=[M,DFF] fp32
// MODE 1: out[token] = gate * (H @ W2 + b2), fused combine scatter
template<int MODE>
__global__ __launch_bounds__(256) void gemm_kernel(
    const unsigned short* __restrict__ A, const float* __restrict__ Bw,
    const float* __restrict__ bias, void* __restrict__ outp,
    const int* __restrict__ slot_token, const float* __restrict__ gate,
    const int* __restrict__ filled)
{
  constexpr int N = MODE ? MDIM : DFF_DIM;
  constexpr int K = MODE ? DFF_DIM : MDIM;
  const int e = blockIdx.z;
  const int rowbase = blockIdx.y * 128;
  const int colbase = blockIdx.x * 128;
  if (rowbase >= filled[e]) return;   // block-uniform early exit

  __shared__ unsigned short As[128][40];  // [m][k], +8 pad vs 32
  __shared__ unsigned short Bs[128][40];  // [n][k]

  const int tid = threadIdx.x;
  const int lane = tid & 63;
  const int wid = tid >> 6;
  const int wm = (wid >> 1) * 64, wn = (wid & 1) * 64;
  const int qm = lane & 15, qk = (lane >> 4) * 8, qr = lane >> 4;

  const unsigned short* Ab = A + ((size_t)e * CAP + rowbase) * K;
  const float* Bb = Bw + (size_t)e * K * N + colbase;

  f32x4 acc[4][4];
  #pragma unroll
  for (int i = 0; i < 4; ++i)
    #pragma unroll
    for (int j = 0; j < 4; ++j)
      #pragma unroll
      for (int r = 0; r < 4; ++r) acc[i][j][r] = 0.0f;

  for (int k0 = 0; k0 < K; k0 += 32) {
    __syncthreads();
    // stage A tile 128x32 bf16 (16B vector loads)
    #pragma unroll
    for (int i = 0; i < 2; ++i) {
      const int c = tid + i * 256;
      const int m = c >> 2, kq = c & 3;
      const uint4 v = *(const uint4*)(Ab + (size_t)m * K + k0 + kq * 8);
      *(uint4*)&As[m][kq * 8] = v;
    }
    // stage B tile 32x128 fp32 -> bf16, stored [n][k] for MFMA B-frag
    #pragma unroll
    for (int i = 0; i < 4; ++i) {
      const int c = tid + i * 256;
      const int n = c & 127, kq = c >> 7;
      const float* bp = Bb + (size_t)(k0 + kq * 4) * N + n;
      ushort4 h;
      h.x = f2bf(bp[0]);
      h.y = f2bf(bp[(size_t)N]);
      h.z = f2bf(bp[(size_t)2 * N]);
      h.w = f2bf(bp[(size_t)3 * N]);
      *(ushort4*)&Bs[n][kq * 4] = h;
    }
    __syncthreads();
    short8 af[4], bfr[4];
    #pragma unroll
    for (int i = 0; i < 4; ++i) af[i] = *(const short8*)&As[wm + i * 16 + qm][qk];
    #pragma unroll
    for (int j = 0; j < 4; ++j) bfr[j] = *(const short8*)&Bs[wn + j * 16 + qm][qk];
    #pragma unroll
    for (int i = 0; i < 4; ++i)
      #pragma unroll
      for (int j = 0; j < 4; ++j)
        acc[i][j] = __builtin_amdgcn_mfma_f32_16x16x32_bf16(af[i], bfr[j], acc[i][j], 0, 0, 0);
  }

  float bcol[4];
  #pragma unroll
  for (int j = 0; j < 4; ++j)
    bcol[j] = bias[(size_t)e * N + colbase + wn + j * 16 + qm];

  if (MODE == 0) {
    unsigned short* Hp = (unsigned short*)outp;
    #pragma unroll
    for (int i = 0; i < 4; ++i) {
      #pragma unroll
      for (int r = 0; r < 4; ++r) {
        const int row = rowbase + wm + i * 16 + qr * 4 + r;
        unsigned short* orow = Hp + ((size_t)e * CAP + row) * N + colbase;
        #pragma unroll
        for (int j = 0; j < 4; ++j) {
          float v = acc[i][j][r] + bcol[j];
          v = v > 0.0f ? v : 0.0f;
          orow[wn + j * 16 + qm] = f2bf(v);
        }
      }
    }
  } else {
    float* Op = (float*)outp;
    #pragma unroll
    for (int i = 0; i < 4; ++i) {
      #pragma unroll
      for (int r = 0; r < 4; ++r) {
        const int row = rowbase + wm + i * 16 + qr * 4 + r;
        const int t = slot_token[e * CAP + row];
        if (t >= 0) {
          const float g = gate[t];
          float* orow = Op + (size_t)t * MDIM + colbase;
          #pragma unroll
          for (int j = 0; j < 4; ++j)
            orow[wn + j * 16 + qm] = g * (acc[i][j][r] + bcol[j]);
        }
      }
    }
  }
}

extern "C" void kernel_launch(void* const* d_in, const int* in_sizes, int n_in,
                              void* d_out, int out_size, void* d_ws, size_t ws_size,
                              hipStream_t stream) {
  const float* x  = (const float*)d_in[0];
  const float* wg = (const float*)d_in[1];
  const float* w1 = (const float*)d_in[2];
  const float* b1 = (const float*)d_in[3];
  const float* w2 = (const float*)d_in[4];
  const float* b2 = (const float*)d_in[5];

  char* ws = (char*)d_ws;
  unsigned short* Abuf = (unsigned short*)ws;                 // E*C*M bf16   = 20,971,520 B
  unsigned short* H    = (unsigned short*)(ws + 20971520);    // E*C*DFF bf16 = 83,886,080 B
  int*   slot_token    = (int*)(ws + 104857600);              // E*C int      = 40,960 B
  int*   eidx          = (int*)(ws + 104898560);              // T int        = 32,768 B
  float* gate          = (float*)(ws + 104931328);            // T float      = 32,768 B
  int*   filled        = (int*)(ws + 104964096);              // E int

  // dropped tokens must output zeros; epilogue only writes kept rows
  hipMemsetAsync(d_out, 0, (size_t)out_size * sizeof(float), stream);

  gate_kernel<<<T_TOKENS, 64, 0, stream>>>(x, wg, eidx, gate);
  scan_kernel<<<1, 1024, 0, stream>>>(eidx, slot_token, filled);
  dispatch_kernel<<<NEXP * CAP, 256, 0, stream>>>(x, slot_token, Abuf);

  dim3 g1(DFF_DIM / 128, CAP / 128, NEXP);
  gemm_kernel<0><<<g1, 256, 0, stream>>>(Abuf, w1, b1, (void*)H, nullptr, nullptr, filled);

  dim3 g2(MDIM / 128, CAP / 128, NEXP);
  gemm_kernel<1><<<g2, 256, 0, stream>>>(H, w2, b2, d_out, slot_token, gate, filled);
}

// Round 2
// 581.811 us; speedup vs baseline: 1.0711x; 1.0711x over previous
//
#include <hip/hip_runtime.h>

#define T_TOKENS 8192
#define MDIM 1024
#define NEXP 8
#define DFF_DIM 4096
#define CAP 1280

typedef __attribute__((ext_vector_type(8))) short short8;
typedef __attribute__((ext_vector_type(4))) float f32x4;

__device__ inline unsigned short f2bf(float f) {
  unsigned u = __float_as_uint(f);
  u = u + 0x7fffu + ((u >> 16) & 1u);
  return (unsigned short)(u >> 16);
}

// async global->LDS DMA, 16B per lane. LDS dst must be wave-uniform base;
// lane i's data lands at base + i*16B (guide §5, m97/m104).
__device__ __forceinline__ void async_ld16(const void* g, void* l) {
  __builtin_amdgcn_global_load_lds(
      (__attribute__((address_space(1))) void*)const_cast<void*>(g),
      (__attribute__((address_space(3))) void*)l, 16, 0, 0);
}

// ---------------- gating: logits in fp64, softmax top-1 ----------------
__global__ __launch_bounds__(64) void gate_kernel(const float* __restrict__ x,
    const float* __restrict__ wg, int* __restrict__ eidx, float* __restrict__ gate)
{
  const int t = blockIdx.x;
  const int lane = threadIdx.x;
  const float* xr = x + (size_t)t * MDIM;
  double acc[NEXP];
  #pragma unroll
  for (int e = 0; e < NEXP; ++e) acc[e] = 0.0;
  for (int m = lane; m < MDIM; m += 64) {
    double xv = (double)xr[m];
    const float* wr = wg + (size_t)m * NEXP;
    #pragma unroll
    for (int e = 0; e < NEXP; ++e) acc[e] += xv * (double)wr[e];
  }
  #pragma unroll
  for (int off = 32; off > 0; off >>= 1) {
    #pragma unroll
    for (int e = 0; e < NEXP; ++e) acc[e] += __shfl_down(acc[e], off);
  }
  if (lane == 0) {
    double mx = acc[0]; int idx = 0;
    #pragma unroll
    for (int e = 1; e < NEXP; ++e) if (acc[e] > mx) { mx = acc[e]; idx = e; }
    double s = 0.0;
    #pragma unroll
    for (int e = 0; e < NEXP; ++e) s += exp(acc[e] - mx);
    eidx[t] = idx;
    gate[t] = (float)(1.0 / s);   // softmax prob of argmax expert
  }
}

// ---------------- order-preserving capacity scan (single block) ----------------
__global__ __launch_bounds__(1024) void scan_kernel(const int* __restrict__ eidx,
    int* __restrict__ slot_token, int* __restrict__ filled)
{
  __shared__ int hist[16][NEXP];
  __shared__ int wpre[16][NEXP];
  __shared__ int rtot[NEXP];
  __shared__ int base[NEXP];
  const int tid = threadIdx.x;
  const int w = tid >> 6, lane = tid & 63;
  for (int i = tid; i < NEXP * CAP; i += 1024) slot_token[i] = -1;
  if (tid < NEXP) base[tid] = 0;
  __syncthreads();
  const unsigned long long lt = (1ull << lane) - 1ull;
  for (int r = 0; r < T_TOKENS / 1024; ++r) {
    const int t = r * 1024 + tid;
    const int e = eidx[t];
    unsigned long long bal[NEXP];
    #pragma unroll
    for (int ee = 0; ee < NEXP; ++ee) bal[ee] = __ballot(e == ee);
    const int rank = __popcll(bal[e] & lt);
    if (lane < NEXP) hist[w][lane] = __popcll(bal[lane]);
    __syncthreads();
    if (tid < 16 * NEXP) {
      int ww = tid >> 3, ee = tid & 7, s = 0;
      for (int j = 0; j < ww; ++j) s += hist[j][ee];
      wpre[ww][ee] = s;
    }
    if (tid < NEXP) {
      int s = 0;
      for (int j = 0; j < 16; ++j) s += hist[j][tid];
      rtot[tid] = s;
    }
    __syncthreads();
    const int pos = base[e] + wpre[w][e] + rank;
    if (pos < CAP) slot_token[e * CAP + pos] = t;
    __syncthreads();
    if (tid < NEXP) base[tid] += rtot[tid];
    __syncthreads();
  }
  if (tid < NEXP) filled[tid] = (base[tid] < CAP) ? base[tid] : CAP;
}

// ---------------- dispatch: gather kept tokens into [E,C,M] bf16 ----------------
__global__ __launch_bounds__(256) void dispatch_kernel(const float* __restrict__ x,
    const int* __restrict__ slot_token, unsigned short* __restrict__ Abuf)
{
  const int row = blockIdx.x;
  const int tid = threadIdx.x;
  const int t = slot_token[row];
  unsigned short* dst = Abuf + (size_t)row * MDIM + tid * 4;
  if (t < 0) {
    ushort4 z; z.x = 0; z.y = 0; z.z = 0; z.w = 0;
    *(ushort4*)dst = z;
  } else {
    const float4 v = *(const float4*)(x + (size_t)t * MDIM + tid * 4);
    ushort4 h;
    h.x = f2bf(v.x); h.y = f2bf(v.y); h.z = f2bf(v.z); h.w = f2bf(v.w);
    *(ushort4*)dst = h;
  }
}

// ------------- weight transpose + fp32->bf16: src [R][Cc] -> dst [Cc][R] -------------
template<int R, int Cc>
__global__ __launch_bounds__(256) void transpose_cvt_kernel(
    const float* __restrict__ src, unsigned short* __restrict__ dst)
{
  __shared__ unsigned short tile[64][66];   // +2 pad: write-phase column reads ~2-way
  const int e = blockIdx.z;
  const int r0 = blockIdx.y * 64;
  const int c0 = blockIdx.x * 64;
  const int t = threadIdx.x;
  const float* S = src + (size_t)e * R * Cc;
  unsigned short* D = dst + (size_t)e * R * Cc;
  const int tr = t >> 4;         // 0..15
  const int tc = (t & 15) * 4;   // 0..60
  #pragma unroll
  for (int i = 0; i < 4; ++i) {
    const int row = i * 16 + tr;
    const float4 v = *(const float4*)(S + (size_t)(r0 + row) * Cc + c0 + tc);
    tile[row][tc + 0] = f2bf(v.x);
    tile[row][tc + 1] = f2bf(v.y);
    tile[row][tc + 2] = f2bf(v.z);
    tile[row][tc + 3] = f2bf(v.w);
  }
  __syncthreads();
  #pragma unroll
  for (int i = 0; i < 4; ++i) {
    const int crow = i * 16 + tr;   // src col index
    ushort4 o;
    o.x = tile[tc + 0][crow];
    o.y = tile[tc + 1][crow];
    o.z = tile[tc + 2][crow];
    o.w = tile[tc + 3][crow];
    *(ushort4*)(D + (size_t)(c0 + crow) * R + r0 + tc) = o;
  }
}

// ---------------- batched expert GEMM, bf16 MFMA 16x16x32, m97-style ----------------
// A [C][K] bf16 row-major, Bt [N][K] bf16 row-major (pre-transposed weights).
// MODE 0: H = relu(A @ W1 + b1) -> bf16.  MODE 1: out[token] = gate*(H @ W2 + b2).
template<int MODE>
__global__ __launch_bounds__(256) void gemm_kernel(
    const unsigned short* __restrict__ A, const unsigned short* __restrict__ Bt,
    const float* __restrict__ bias, void* __restrict__ outp,
    const int* __restrict__ slot_token, const float* __restrict__ gate,
    const int* __restrict__ filled)
{
  constexpr int N = MODE ? MDIM : DFF_DIM;
  constexpr int K = MODE ? DFF_DIM : MDIM;
  const int e = blockIdx.z;
  const int rowbase = blockIdx.y * 128;
  const int colbase = blockIdx.x * 128;
  if (rowbase >= filled[e]) return;   // block-uniform early exit

  // unpadded: layout must equal global_load_lds lane order (m104 caveat)
  __shared__ unsigned short As[128 * 32];
  __shared__ unsigned short Bs[128 * 32];

  const int tid = threadIdx.x;
  const int lane = tid & 63;
  const int wid = tid >> 6;
  const int wm = (wid >> 1) * 64, wn = (wid & 1) * 64;
  const int qm = lane & 15, qk = (lane >> 4) * 8, qr = lane >> 4;

  const unsigned short* Ab = A + ((size_t)e * CAP + rowbase) * K;
  const unsigned short* Bb = Bt + ((size_t)e * N + colbase) * K;

  // staging geometry: round r, wave w, lane l stages 16B of row (r*64+w*16+(l>>2)),
  // k-chunk (l&3)*8 -> LDS element r*2048 + w*512 + l*8  (= row*32 + kchunk)
  const int ldr = wid * 16 + (lane >> 2);
  const int ldk = (lane & 3) * 8;
  const unsigned short* ag = Ab + (size_t)ldr * K + ldk;
  const unsigned short* bg = Bb + (size_t)ldr * K + ldk;
  unsigned short* asw = As + wid * 512;
  unsigned short* bsw = Bs + wid * 512;

  f32x4 acc[4][4];
  #pragma unroll
  for (int i = 0; i < 4; ++i)
    #pragma unroll
    for (int j = 0; j < 4; ++j)
      #pragma unroll
      for (int r = 0; r < 4; ++r) acc[i][j][r] = 0.0f;

  for (int k0 = 0; k0 < K; k0 += 32) {
    __syncthreads();   // previous iter's ds_reads done before overwrite
    async_ld16(ag + k0,                asw);
    async_ld16(ag + (size_t)64 * K + k0, asw + 2048);
    async_ld16(bg + k0,                bsw);
    async_ld16(bg + (size_t)64 * K + k0, bsw + 2048);
    __syncthreads();   // compiler drains vmcnt before barrier -> LDS valid
    short8 af[4], bfr[4];
    #pragma unroll
    for (int i = 0; i < 4; ++i) af[i] = *(const short8*)(As + (wm + i * 16 + qm) * 32 + qk);
    #pragma unroll
    for (int j = 0; j < 4; ++j) bfr[j] = *(const short8*)(Bs + (wn + j * 16 + qm) * 32 + qk);
    #pragma unroll
    for (int i = 0; i < 4; ++i)
      #pragma unroll
      for (int j = 0; j < 4; ++j)
        acc[i][j] = __builtin_amdgcn_mfma_f32_16x16x32_bf16(af[i], bfr[j], acc[i][j], 0, 0, 0);
  }

  float bcol[4];
  #pragma unroll
  for (int j = 0; j < 4; ++j)
    bcol[j] = bias[(size_t)e * N + colbase + wn + j * 16 + qm];

  if (MODE == 0) {
    unsigned short* Hp = (unsigned short*)outp;
    #pragma unroll
    for (int i = 0; i < 4; ++i) {
      #pragma unroll
      for (int r = 0; r < 4; ++r) {
        const int row = rowbase + wm + i * 16 + qr * 4 + r;
        unsigned short* orow = Hp + ((size_t)e * CAP + row) * N + colbase;
        #pragma unroll
        for (int j = 0; j < 4; ++j) {
          float v = acc[i][j][r] + bcol[j];
          v = v > 0.0f ? v : 0.0f;
          orow[wn + j * 16 + qm] = f2bf(v);
        }
      }
    }
  } else {
    float* Op = (float*)outp;
    #pragma unroll
    for (int i = 0; i < 4; ++i) {
      #pragma unroll
      for (int r = 0; r < 4; ++r) {
        const int row = rowbase + wm + i * 16 + qr * 4 + r;
        const int t = slot_token[e * CAP + row];
        if (t >= 0) {
          const float g = gate[t];
          float* orow = Op + (size_t)t * MDIM + colbase;
          #pragma unroll
          for (int j = 0; j < 4; ++j)
            orow[wn + j * 16 + qm] = g * (acc[i][j][r] + bcol[j]);
        }
      }
    }
  }
}

extern "C" void kernel_launch(void* const* d_in, const int* in_sizes, int n_in,
                              void* d_out, int out_size, void* d_ws, size_t ws_size,
                              hipStream_t stream) {
  const float* x  = (const float*)d_in[0];
  const float* wg = (const float*)d_in[1];
  const float* w1 = (const float*)d_in[2];
  const float* b1 = (const float*)d_in[3];
  const float* w2 = (const float*)d_in[4];
  const float* b2 = (const float*)d_in[5];

  char* ws = (char*)d_ws;
  unsigned short* Abuf = (unsigned short*)ws;                 // E*C*M bf16    20,971,520 B
  unsigned short* H    = (unsigned short*)(ws + 20971520);    // E*C*DFF bf16  83,886,080 B
  unsigned short* Wt   = (unsigned short*)(ws + 104857600);   // E*4096*1024 bf16 = 67,108,864 B (reused W1T then W2T)
  int*   slot_token    = (int*)(ws + 171966464);              // E*C int       40,960 B
  int*   eidx          = (int*)(ws + 172007424);              // T int         32,768 B
  float* gate          = (float*)(ws + 172040192);            // T float       32,768 B
  int*   filled        = (int*)(ws + 172072960);              // E int

  // dropped tokens must output zeros; epilogue only writes kept rows
  hipMemsetAsync(d_out, 0, (size_t)out_size * sizeof(float), stream);

  gate_kernel<<<T_TOKENS, 64, 0, stream>>>(x, wg, eidx, gate);
  scan_kernel<<<1, 1024, 0, stream>>>(eidx, slot_token, filled);
  dispatch_kernel<<<NEXP * CAP, 256, 0, stream>>>(x, slot_token, Abuf);

  // W1 [E][M][DFF] fp32 -> Wt [E][DFF][M] bf16
  dim3 gc1(DFF_DIM / 64, MDIM / 64, NEXP);
  transpose_cvt_kernel<MDIM, DFF_DIM><<<gc1, 256, 0, stream>>>(w1, Wt);

  dim3 g1(DFF_DIM / 128, CAP / 128, NEXP);
  gemm_kernel<0><<<g1, 256, 0, stream>>>(Abuf, Wt, b1, (void*)H, nullptr, nullptr, filled);

  // W2 [E][DFF][M] fp32 -> Wt [E][M][DFF] bf16 (reuse buffer; stream-ordered after gemm1)
  dim3 gc2(MDIM / 64, DFF_DIM / 64, NEXP);
  transpose_cvt_kernel<DFF_DIM, MDIM><<<gc2, 256, 0, stream>>>(w2, Wt);

  dim3 g2(MDIM / 128, CAP / 128, NEXP);
  gemm_kernel<1><<<g2, 256, 0, stream>>>(H, Wt, b2, d_out, slot_token, gate, filled);
}